// Round 1
// baseline (7155.350 us; speedup 1.0000x reference)
//
#include <hip/hip_runtime.h>
#include <hip/hip_bf16.h>
#include <cstdint>

#define NB 64        // batch
#define ND 64        // DIM
#define NH 8         // heads
#define DH 64        // dim_head
#define NIN 512      // inner
#define NMLP 256
#define NDEPTH 4
#define NPATCH 225
#define NTOK 226
#define NSB 128      // 2*B (both streams batched)
#define NROWS (NSB*NTOK)   // 28928
#define AP 230             // attention LDS pitch in u16 (115 words, gcd(115,32)=1)

__device__ __forceinline__ float b2f(unsigned short h) {
  uint32_t v = ((uint32_t)h) << 16; float f; __builtin_memcpy(&f, &v, 4); return f;
}
__device__ __forceinline__ float b2f_lo(uint32_t u) {
  uint32_t v = u << 16; float f; __builtin_memcpy(&f, &v, 4); return f;
}
__device__ __forceinline__ float b2f_hi(uint32_t u) {
  uint32_t v = u & 0xffff0000u; float f; __builtin_memcpy(&f, &v, 4); return f;
}
__device__ __forceinline__ unsigned short f2b(float f) {
  __hip_bfloat16 h = __float2bfloat16(f);
  unsigned short u; __builtin_memcpy(&u, &h, 2); return u;
}

// ---- fusion-matrix diagonal: sdfm[b][d] = sqrt(sigmoid(x @ fmg_w[:,65d])) ----
__global__ void k_dfm(const float* __restrict__ hsi, const float* __restrict__ lidar,
                      const float* __restrict__ fmg_w, float* __restrict__ sdfm) {
  __shared__ float xc[128];
  int b = blockIdx.x, t = threadIdx.x;
  const float* src = (t < 64) ? hsi : lidar;
  int d = t & 63;
  const float* p = src + ((size_t)b * 64 + d) * NPATCH;
  float s = 0.f;
  for (int i = 0; i < NPATCH; ++i) s += p[i];
  xc[t] = s * (1.0f / 225.0f);
  __syncthreads();
  if (t < 64) {
    float acc = 0.f;
    const float* w = fmg_w + t * 65;       // column 65*t of [128,4096]
    for (int c = 0; c < 128; ++c) acc += xc[c] * w[c * 4096];
    float sg = 1.0f / (1.0f + expf(-acc));
    sdfm[b * 64 + t] = sqrtf(sg);
  }
}

// ---- build X[2B, 226, 64]: cls + patches(from hsi for BOTH streams) + pos ----
__global__ void k_build(const float* __restrict__ hsi,
                        const float* __restrict__ cls_h, const float* __restrict__ cls_l,
                        const float* __restrict__ pos_h, const float* __restrict__ pos_l,
                        float* __restrict__ X) {
  int r = blockIdx.x;                 // sb*226 + n
  int sb = r / NTOK, n = r - sb * NTOK;
  int s = sb >> 6, b = sb & 63;
  int d = threadIdx.x;
  float v;
  if (n == 0) v = s ? cls_l[d] : cls_h[d];
  else        v = hsi[((size_t)b * 64 + d) * NPATCH + (n - 1)];
  const float* pos = s ? pos_l : pos_h;
  X[(size_t)r * ND + d] = v + pos[n * ND + d];
}

// ---- fused LN1 + Q,V projection; fold sqrt(dfm)*sqrt(scale) into Q ----
__global__ __launch_bounds__(256) void k_qkv(const float* __restrict__ X,
    const float* __restrict__ g, const float* __restrict__ bb,
    const float* __restrict__ W, const float* __restrict__ sdfm,
    uint16_t* __restrict__ Qg, uint16_t* __restrict__ Vg) {
  __shared__ float xn[16][64];
  int t = threadIdx.x;
  int r0 = blockIdx.x * 16;
  if (t < 16) {
    const float* xr = X + (size_t)(r0 + t) * ND;
    float m = 0.f;
    for (int d = 0; d < 64; ++d) m += xr[d];
    m *= (1.f / 64.f);
    float v = 0.f;
    for (int d = 0; d < 64; ++d) { float df = xr[d] - m; v += df * df; }
    v *= (1.f / 64.f);
    float rs = rsqrtf(v + 1e-5f);
    for (int d = 0; d < 64; ++d) xn[t][d] = (xr[d] - m) * rs * g[d] + bb[d];
  }
  __syncthreads();
  float a0[16], a1[16], a2[16], a3[16];
  #pragma unroll
  for (int m = 0; m < 16; ++m) { a0[m] = 0.f; a1[m] = 0.f; a2[m] = 0.f; a3[m] = 0.f; }
  for (int d = 0; d < 64; ++d) {
    const float* wr = W + d * 1536;
    float w0 = wr[t], w1 = wr[t + 256];            // q cols t, t+256
    float w2 = wr[1024 + t], w3 = wr[1280 + t];    // v cols t, t+256
    #pragma unroll
    for (int m = 0; m < 16; ++m) {
      float x = xn[m][d];
      a0[m] += x * w0; a1[m] += x * w1; a2[m] += x * w2; a3[m] += x * w3;
    }
  }
  int dh = t & 63;
  #pragma unroll
  for (int m = 0; m < 16; ++m) {
    int r = r0 + m;
    int b = (r / NTOK) & 63;
    float f = sdfm[b * 64 + dh] * 0.35355339059327373f;  // sqrt(1/8)
    size_t row = (size_t)r * NIN;
    Qg[row + t]       = f2b(a0[m] * f);
    Qg[row + t + 256] = f2b(a1[m] * f);
    Vg[row + t]       = f2b(a2[m]);
    Vg[row + t + 256] = f2b(a3[m]);
  }
}

// ---- attention: one block per (sb, h); Q,V staged transposed in LDS (bf16) ----
__global__ __launch_bounds__(256) void k_attn(const uint16_t* __restrict__ Qg,
    const uint16_t* __restrict__ Vg, uint16_t* __restrict__ Og) {
  __shared__ __align__(16) unsigned short sm[31488];   // 62976 B total
  unsigned short* qs = sm;                 // [64][AP]  q*sqrt(dfm*scale), transposed [d][j]
  unsigned short* vt = sm + 64 * AP;       // [64][AP]  v transposed [d][j]
  float* pl = (float*)(sm + 2 * 64 * AP);  // [4][256]  per-wave softmax row
  int bh = blockIdx.x;
  int sb = bh >> 3, h = bh & 7;
  int t = threadIdx.x;
  const uint16_t* Qb = Qg + (size_t)sb * NTOK * NIN + h * DH;
  const uint16_t* Vb = Vg + (size_t)sb * NTOK * NIN + h * DH;
  for (int idx = t; idx < NTOK * 32; idx += 256) {
    int j = idx >> 5, d2 = (idx & 31) << 1;
    uint32_t q2 = *(const uint32_t*)(Qb + (size_t)j * NIN + d2);
    uint32_t v2 = *(const uint32_t*)(Vb + (size_t)j * NIN + d2);
    qs[d2 * AP + j]       = (unsigned short)(q2 & 0xffffu);
    qs[(d2 + 1) * AP + j] = (unsigned short)(q2 >> 16);
    vt[d2 * AP + j]       = (unsigned short)(v2 & 0xffffu);
    vt[(d2 + 1) * AP + j] = (unsigned short)(v2 >> 16);
  }
  __syncthreads();
  int w = t >> 6, l = t & 63;
  float* plw = pl + w * 256;
  const unsigned short* vrow = vt + l * AP;
  for (int i = w; i < NTOK; i += 4) {
    float s0 = 0.f, s1 = 0.f, s2 = 0.f, s3 = 0.f;
    #pragma unroll 4
    for (int d = 0; d < 64; ++d) {
      const unsigned short* row = qs + d * AP;
      float qi = b2f(row[i]);                                 // broadcast
      uint32_t ua = *(const uint32_t*)(row + 2 * l);          // j = 2l, 2l+1
      uint32_t ub = *(const uint32_t*)(row + 2 * l + 128);    // j = 2l+128, 2l+129
      s0 += qi * b2f_lo(ua);
      s1 += qi * b2f_hi(ua);
      s2 += qi * b2f_lo(ub);
      s3 += qi * b2f_hi(ub);
    }
    // mask invalid j (>=226); j0,j1 <= 127 always valid
    if (2 * l + 128 >= NTOK) s2 = -INFINITY;
    if (2 * l + 129 >= NTOK) s3 = -INFINITY;
    float mx = fmaxf(fmaxf(s0, s1), fmaxf(s2, s3));
    #pragma unroll
    for (int o = 32; o; o >>= 1) mx = fmaxf(mx, __shfl_xor(mx, o));
    float p0 = expf(s0 - mx), p1 = expf(s1 - mx);
    float p2 = expf(s2 - mx), p3 = expf(s3 - mx);
    float sum = p0 + p1 + p2 + p3;
    #pragma unroll
    for (int o = 32; o; o >>= 1) sum += __shfl_xor(sum, o);
    float rinv = 1.f / sum;
    *(float2*)(plw + 2 * l)       = make_float2(p0, p1);
    *(float2*)(plw + 2 * l + 128) = make_float2(p2, p3);
    asm volatile("s_waitcnt lgkmcnt(0)" ::: "memory");
    float acc = 0.f;
    for (int jp = 0; jp < 113; ++jp) {                        // j pairs 0..225
      float2 pp = *(const float2*)(plw + 2 * jp);             // broadcast
      uint32_t uv = *(const uint32_t*)(vrow + 2 * jp);
      acc += pp.x * b2f_lo(uv) + pp.y * b2f_hi(uv);
    }
    Og[((size_t)sb * NTOK + i) * NIN + h * DH + l] = f2b(acc * rinv);
  }
}

// ---- out-projection + residual: X += O @ Wo + bo ----
__global__ __launch_bounds__(256) void k_proj(const uint16_t* __restrict__ Og,
    const float* __restrict__ Wo, const float* __restrict__ bo, float* __restrict__ X) {
  __shared__ unsigned short ol[32][512];   // 32 KB
  int t = threadIdx.x;
  int r0 = blockIdx.x * 32;
  const uint32_t* src = (const uint32_t*)(Og + (size_t)r0 * NIN);
  uint32_t* dst = (uint32_t*)ol;
  for (int idx = t; idx < 32 * 256; idx += 256) dst[idx] = src[idx];
  __syncthreads();
  int w = t >> 6, l = t & 63;
  float acc[8];
  #pragma unroll
  for (int m = 0; m < 8; ++m) acc[m] = 0.f;
  for (int c = 0; c < 512; ++c) {
    float wv = Wo[c * 64 + l];
    #pragma unroll
    for (int m = 0; m < 8; ++m) acc[m] += b2f(ol[w + m * 4][c]) * wv;
  }
  float bv = bo[l];
  #pragma unroll
  for (int m = 0; m < 8; ++m) {
    size_t r = (size_t)(r0 + w + m * 4);
    X[r * ND + l] += acc[m] + bv;
  }
}

// ---- fused LN2 + FF (gelu exact) + residual ----
__global__ __launch_bounds__(256) void k_ff(float* __restrict__ X,
    const float* __restrict__ g, const float* __restrict__ bb,
    const float* __restrict__ W1, const float* __restrict__ b1,
    const float* __restrict__ W2, const float* __restrict__ b2) {
  __shared__ float xn[16][64];
  __shared__ float hl[16][256];
  int t = threadIdx.x;
  int r0 = blockIdx.x * 16;
  if (t < 16) {
    const float* xr = X + (size_t)(r0 + t) * ND;
    float m = 0.f;
    for (int d = 0; d < 64; ++d) m += xr[d];
    m *= (1.f / 64.f);
    float v = 0.f;
    for (int d = 0; d < 64; ++d) { float df = xr[d] - m; v += df * df; }
    v *= (1.f / 64.f);
    float rs = rsqrtf(v + 1e-5f);
    for (int d = 0; d < 64; ++d) xn[t][d] = (xr[d] - m) * rs * g[d] + bb[d];
  }
  __syncthreads();
  float a[16];
  #pragma unroll
  for (int m = 0; m < 16; ++m) a[m] = 0.f;
  for (int d = 0; d < 64; ++d) {
    float wv = W1[d * 256 + t];
    #pragma unroll
    for (int m = 0; m < 16; ++m) a[m] += xn[m][d] * wv;
  }
  float bv = b1[t];
  #pragma unroll
  for (int m = 0; m < 16; ++m) {
    float z = a[m] + bv;
    hl[m][t] = 0.5f * z * (1.f + erff(z * 0.7071067811865476f));  // exact gelu
  }
  __syncthreads();
  int w = t >> 6, l = t & 63;
  float acc[4] = {0.f, 0.f, 0.f, 0.f};
  for (int c = 0; c < 256; ++c) {
    float wv = W2[c * 64 + l];
    #pragma unroll
    for (int m = 0; m < 4; ++m) acc[m] += hl[w + m * 4][c] * wv;
  }
  float b2v = b2[l];
  #pragma unroll
  for (int m = 0; m < 4; ++m) {
    size_t r = (size_t)(r0 + w + m * 4);
    X[r * ND + l] += acc[m] + b2v;
  }
}

// ---- swap cls tokens between streams ----
__global__ void k_xchg(float* __restrict__ X) {
  int i = blockIdx.x * 64 + threadIdx.x;   // b*64 + d
  int b = i >> 6, d = i & 63;
  size_t i0 = (size_t)b * NTOK * ND + d;          // stream 0, n=0
  size_t i1 = (size_t)(64 + b) * NTOK * ND + d;   // stream 1, n=0
  float a = X[i0], c = X[i1];
  X[i0] = c; X[i1] = a;
}

// ---- final: out = h_cls + l_cls ----
__global__ void k_out(const float* __restrict__ X, float* __restrict__ out) {
  int i = blockIdx.x * 64 + threadIdx.x;
  int b = i >> 6, d = i & 63;
  out[i] = X[(size_t)b * NTOK * ND + d] + X[(size_t)(64 + b) * NTOK * ND + d];
}

extern "C" void kernel_launch(void* const* d_in, const int* in_sizes, int n_in,
                              void* d_out, int out_size, void* d_ws, size_t ws_size,
                              hipStream_t stream) {
  const float* hsi   = (const float*)d_in[0];
  const float* lidar = (const float*)d_in[1];
  const float* cls_h = (const float*)d_in[2];
  const float* cls_l = (const float*)d_in[3];
  const float* pos_h = (const float*)d_in[4];
  const float* pos_l = (const float*)d_in[5];
  const float* fmg_w = (const float*)d_in[6];
  const float* ln1_g = (const float*)d_in[7];
  const float* ln1_b = (const float*)d_in[8];
  const float* qkv_w = (const float*)d_in[9];
  const float* out_w = (const float*)d_in[10];
  const float* out_b = (const float*)d_in[11];
  const float* ln2_g = (const float*)d_in[12];
  const float* ln2_b = (const float*)d_in[13];
  const float* ff_w1 = (const float*)d_in[14];
  const float* ff_b1 = (const float*)d_in[15];
  const float* ff_w2 = (const float*)d_in[16];
  const float* ff_b2 = (const float*)d_in[17];

  char* ws = (char*)d_ws;
  float* X      = (float*)ws;                      // 28928*64*4      = 7,405,568 B
  float* sdfm   = (float*)(ws + 7405568);          // 64*64*4         = 16,384 B
  uint16_t* Q   = (uint16_t*)(ws + 7421952);       // 28928*512*2     = 29,622,272 B
  uint16_t* V   = (uint16_t*)(ws + 37044224);      // 28928*512*2     = 29,622,272 B
  uint16_t* O   = Q;   // O aliases Q: each attn block reads its slice into LDS first

  k_dfm<<<NB, 128, 0, stream>>>(hsi, lidar, fmg_w, sdfm);
  k_build<<<NROWS, 64, 0, stream>>>(hsi, cls_h, cls_l, pos_h, pos_l, X);
  for (int pass = 0; pass < 2; ++pass) {
    for (int ly = 0; ly < NDEPTH; ++ly) {
      k_qkv<<<NROWS / 16, 256, 0, stream>>>(X, ln1_g + ly * ND, ln1_b + ly * ND,
                                            qkv_w + (size_t)ly * ND * 3 * NIN, sdfm, Q, V);
      k_attn<<<NSB * NH, 256, 0, stream>>>(Q, V, O);
      k_proj<<<NROWS / 32, 256, 0, stream>>>(O, out_w + (size_t)ly * NIN * ND,
                                             out_b + ly * ND, X);
      k_ff<<<NROWS / 16, 256, 0, stream>>>(X, ln2_g + ly * ND, ln2_b + ly * ND,
                                           ff_w1 + (size_t)ly * ND * NMLP, ff_b1 + ly * NMLP,
                                           ff_w2 + (size_t)ly * NMLP * ND, ff_b2 + ly * ND);
    }
    if (pass == 0) k_xchg<<<64, 64, 0, stream>>>(X);
  }
  k_out<<<64, 64, 0, stream>>>(X, (float*)d_out);
}

// Round 3
// 2013.991 us; speedup vs baseline: 3.5528x; 3.5528x over previous
//
#include <hip/hip_runtime.h>
#include <hip/hip_bf16.h>
#include <cstdint>

#define NB 64        // batch
#define ND 64        // DIM
#define NH 8         // heads
#define DH 64        // dim_head
#define NIN 512      // inner
#define NMLP 256
#define NDEPTH 4
#define NPATCH 225
#define NTOK 226
#define NSB 128      // 2*B (both streams batched)
#define NROWS (NSB*NTOK)   // 28928

#define QP 64        // Qs LDS pitch (bf16 units)
#define VP 240       // Vt LDS pitch (bf16 units)

typedef __attribute__((ext_vector_type(8))) short bfrag8;
typedef __attribute__((ext_vector_type(4))) float ffrag4;

__device__ __forceinline__ float b2f(unsigned short h) {
  uint32_t v = ((uint32_t)h) << 16; float f; __builtin_memcpy(&f, &v, 4); return f;
}
__device__ __forceinline__ unsigned short f2b(float f) {
  __hip_bfloat16 h = __float2bfloat16(f);
  unsigned short u; __builtin_memcpy(&u, &h, 2); return u;
}

// ---- fusion-matrix diagonal: sdfm[b][d] = sqrt(sigmoid(x @ fmg_w[:,65d])) ----
__global__ void k_dfm(const float* __restrict__ hsi, const float* __restrict__ lidar,
                      const float* __restrict__ fmg_w, float* __restrict__ sdfm) {
  __shared__ float xc[128];
  int b = blockIdx.x, t = threadIdx.x;
  const float* src = (t < 64) ? hsi : lidar;
  int d = t & 63;
  const float* p = src + ((size_t)b * 64 + d) * NPATCH;
  float s = 0.f;
  for (int i = 0; i < NPATCH; ++i) s += p[i];
  xc[t] = s * (1.0f / 225.0f);
  __syncthreads();
  if (t < 64) {
    float acc = 0.f;
    const float* w = fmg_w + t * 65;       // column 65*t of [128,4096]
    for (int c = 0; c < 128; ++c) acc += xc[c] * w[c * 4096];
    float sg = 1.0f / (1.0f + expf(-acc));
    sdfm[b * 64 + t] = sqrtf(sg);
  }
}

// ---- build X[2B, 226, 64]: cls + patches(from hsi for BOTH streams) + pos ----
__global__ void k_build(const float* __restrict__ hsi,
                        const float* __restrict__ cls_h, const float* __restrict__ cls_l,
                        const float* __restrict__ pos_h, const float* __restrict__ pos_l,
                        float* __restrict__ X) {
  int r = blockIdx.x;                 // sb*226 + n
  int sb = r / NTOK, n = r - sb * NTOK;
  int s = sb >> 6, b = sb & 63;
  int d = threadIdx.x;
  float v;
  if (n == 0) v = s ? cls_l[d] : cls_h[d];
  else        v = hsi[((size_t)b * 64 + d) * NPATCH + (n - 1)];
  const float* pos = s ? pos_l : pos_h;
  X[(size_t)r * ND + d] = v + pos[n * ND + d];
}

// ---- fused LN1 + Q,V projection; fold sqrt(dfm)*sqrt(scale) into Q ----
__global__ __launch_bounds__(256) void k_qkv(const float* __restrict__ X,
    const float* __restrict__ g, const float* __restrict__ bb,
    const float* __restrict__ W, const float* __restrict__ sdfm,
    uint16_t* __restrict__ Qg, uint16_t* __restrict__ Vg) {
  __shared__ float xn[16][64];
  int t = threadIdx.x;
  int r0 = blockIdx.x * 16;
  if (t < 16) {
    const float* xr = X + (size_t)(r0 + t) * ND;
    float m = 0.f;
    for (int d = 0; d < 64; ++d) m += xr[d];
    m *= (1.f / 64.f);
    float v = 0.f;
    for (int d = 0; d < 64; ++d) { float df = xr[d] - m; v += df * df; }
    v *= (1.f / 64.f);
    float rs = rsqrtf(v + 1e-5f);
    for (int d = 0; d < 64; ++d) xn[t][d] = (xr[d] - m) * rs * g[d] + bb[d];
  }
  __syncthreads();
  float a0[16], a1[16], a2[16], a3[16];
  #pragma unroll
  for (int m = 0; m < 16; ++m) { a0[m] = 0.f; a1[m] = 0.f; a2[m] = 0.f; a3[m] = 0.f; }
  for (int d = 0; d < 64; ++d) {
    const float* wr = W + d * 1536;
    float w0 = wr[t], w1 = wr[t + 256];            // q cols t, t+256
    float w2 = wr[1024 + t], w3 = wr[1280 + t];    // v cols t, t+256
    #pragma unroll
    for (int m = 0; m < 16; ++m) {
      float x = xn[m][d];
      a0[m] += x * w0; a1[m] += x * w1; a2[m] += x * w2; a3[m] += x * w3;
    }
  }
  int dh = t & 63;
  #pragma unroll
  for (int m = 0; m < 16; ++m) {
    int r = r0 + m;
    int b = (r / NTOK) & 63;
    float f = sdfm[b * 64 + dh] * 0.35355339059327373f;  // sqrt(1/8)
    size_t row = (size_t)r * NIN;
    Qg[row + t]       = f2b(a0[m] * f);
    Qg[row + t + 256] = f2b(a1[m] * f);
    Vg[row + t]       = f2b(a2[m]);
    Vg[row + t + 256] = f2b(a3[m]);
  }
}

// ---- MFMA attention: one block per (sb, h); 4 waves; tokens padded to 240 ----
// S = Qs Qs^T via 16x16x32 bf16 MFMA (A-frag and B-frag patterns identical for
// a self-product). Softmax in C-layout regs; P -> A-layout via 1KB/wave LDS
// round trip; PV from LDS-transposed V. LDS total = 65536 B exactly.
__global__ __launch_bounds__(256) void k_attn(const uint16_t* __restrict__ Qg,
    const uint16_t* __restrict__ Vg, uint16_t* __restrict__ Og) {
  __shared__ __align__(16) uint16_t qs[240 * QP];   // 30720 B, rows 226..239 zeroed
  __shared__ __align__(16) uint16_t vt[64 * VP];    // 30720 B, cols 226..239 zeroed
  __shared__ __align__(16) uint16_t pb[4][512];     // 4096 B: per-wave P chunk [16][32]
  int bh = blockIdx.x;
  int sb = bh >> 3, h = bh & 7;
  int t = threadIdx.x, w = t >> 6, l = t & 63;
  const uint16_t* Qb = Qg + (size_t)sb * NTOK * NIN + h * DH;
  const uint16_t* Vb = Vg + (size_t)sb * NTOK * NIN + h * DH;

  // stage Q rows: 226 tokens x 64 bf16 = 8 chunks of 8 bf16 (16 B) per row
  // (R2 bug: used NTOK*4 / p&3 -> only d 0..31 staged, d 32..63 was garbage)
  for (int idx = t; idx < NTOK * 8; idx += 256) {
    int j = idx >> 3, p = idx & 7;
    *(bfrag8*)(qs + j * QP + p * 8) = *(const bfrag8*)(Qb + (size_t)j * NIN + p * 8);
  }
  // zero Q pad rows 226..239
  for (int idx = t; idx < 14 * 8; idx += 256) {
    int j = 226 + (idx >> 3), p = idx & 7;
    *(uint4*)(qs + j * QP + p * 8) = make_uint4(0, 0, 0, 0);
  }
  // stage V transposed: vt[d][j] (b16 scatter; once per block, cost amortized)
  for (int idx = t; idx < NTOK * 32; idx += 256) {
    int j = idx >> 5, d2 = (idx & 31) << 1;
    uint32_t v2 = *(const uint32_t*)(Vb + (size_t)j * NIN + d2);
    vt[d2 * VP + j]       = (uint16_t)(v2 & 0xffffu);
    vt[(d2 + 1) * VP + j] = (uint16_t)(v2 >> 16);
  }
  // zero vt cols 226..239 (7 u32 per row; 226 even so 4B-aligned)
  for (int idx = t; idx < 64 * 7; idx += 256) {
    int d = idx / 7, c = 226 + 2 * (idx % 7);
    *(uint32_t*)(vt + d * VP + c) = 0;
  }
  __syncthreads();

  int quad = l >> 4, c = l & 15;
  uint16_t* pw = &pb[w][0];

  for (int it = w; it < 15; it += 4) {
    int i0 = it * 16;
    // A-frags for this i-tile (K=64 -> two K32 chunks)
    bfrag8 a0 = *(const bfrag8*)(qs + (i0 + c) * QP + quad * 8);
    bfrag8 a1 = *(const bfrag8*)(qs + (i0 + c) * QP + 32 + quad * 8);
    // S row-strip: 15 j-tiles
    ffrag4 acc[15];
    #pragma unroll
    for (int jt = 0; jt < 15; ++jt) {
      bfrag8 b0 = *(const bfrag8*)(qs + (jt * 16 + c) * QP + quad * 8);
      bfrag8 b1 = *(const bfrag8*)(qs + (jt * 16 + c) * QP + 32 + quad * 8);
      ffrag4 z = {0.f, 0.f, 0.f, 0.f};
      z = __builtin_amdgcn_mfma_f32_16x16x32_bf16(a0, b0, z, 0, 0, 0);
      z = __builtin_amdgcn_mfma_f32_16x16x32_bf16(a1, b1, z, 0, 0, 0);
      acc[jt] = z;
    }
    // softmax per row r (C-layout: col j = jt*16+c, row i = i0+quad*4+r)
    float rinv[4];
    #pragma unroll
    for (int r = 0; r < 4; ++r) {
      float m = -1e30f;
      #pragma unroll
      for (int jt = 0; jt < 15; ++jt) m = fmaxf(m, acc[jt][r]);
      #pragma unroll
      for (int o = 8; o; o >>= 1) m = fmaxf(m, __shfl_xor(m, o));
      float s = 0.f;
      #pragma unroll
      for (int jt = 0; jt < 15; ++jt) {
        float p = __expf(acc[jt][r] - m);
        if (jt == 14 && c >= 2) p = 0.f;   // j = 224+c >= 226 invalid
        acc[jt][r] = p;
        s += p;
      }
      #pragma unroll
      for (int o = 8; o; o >>= 1) s += __shfl_xor(s, o);
      rinv[r] = 1.f / s;
    }
    // PV: O[i-tile][64] over 8 K32 chunks (last = K16 tail with zeroed upper P)
    ffrag4 oa[4];
    #pragma unroll
    for (int dt = 0; dt < 4; ++dt) oa[dt] = (ffrag4){0.f, 0.f, 0.f, 0.f};
    for (int jc = 0; jc < 8; ++jc) {
      if (jc == 7) {
        // zero P cols 16..31 so the duplicated tail B-reads contribute 0
        *(uint64_t*)(pw + c * 32 + 16 + quad * 4) = 0ull;
      }
      #pragma unroll
      for (int r = 0; r < 4; ++r) {
        int row = quad * 4 + r;
        pw[row * 32 + c] = f2b(acc[2 * jc][r] * rinv[r]);
        if (jc < 7) pw[row * 32 + 16 + c] = f2b(acc[2 * jc + 1][r] * rinv[r]);
      }
      bfrag8 pa = *(const bfrag8*)(pw + c * 32 + quad * 8);   // A-frag of P
      int j0 = jc * 32;
      #pragma unroll
      for (int dt = 0; dt < 4; ++dt) {
        bfrag8 vb;
        if (jc < 7)
          vb = *(const bfrag8*)(vt + (dt * 16 + c) * VP + j0 + quad * 8);
        else
          vb = *(const bfrag8*)(vt + (dt * 16 + c) * VP + 224 + (quad & 1) * 8);
        oa[dt] = __builtin_amdgcn_mfma_f32_16x16x32_bf16(pa, vb, oa[dt], 0, 0, 0);
      }
    }
    // store O (D-layout: row i = i0+quad*4+r, col d = dt*16+c)
    #pragma unroll
    for (int dt = 0; dt < 4; ++dt) {
      #pragma unroll
      for (int r = 0; r < 4; ++r) {
        int i = i0 + quad * 4 + r;
        if (i < NTOK)
          Og[((size_t)sb * NTOK + i) * NIN + h * DH + dt * 16 + c] = f2b(oa[dt][r]);
      }
    }
  }
}

// ---- out-projection + residual: X += O @ Wo + bo ----
__global__ __launch_bounds__(256) void k_proj(const uint16_t* __restrict__ Og,
    const float* __restrict__ Wo, const float* __restrict__ bo, float* __restrict__ X) {
  __shared__ unsigned short ol[32][512];   // 32 KB
  int t = threadIdx.x;
  int r0 = blockIdx.x * 32;
  const uint32_t* src = (const uint32_t*)(Og + (size_t)r0 * NIN);
  uint32_t* dst = (uint32_t*)ol;
  for (int idx = t; idx < 32 * 256; idx += 256) dst[idx] = src[idx];
  __syncthreads();
  int w = t >> 6, l = t & 63;
  float acc[8];
  #pragma unroll
  for (int m = 0; m < 8; ++m) acc[m] = 0.f;
  for (int c = 0; c < 512; ++c) {
    float wv = Wo[c * 64 + l];
    #pragma unroll
    for (int m = 0; m < 8; ++m) acc[m] += b2f(ol[w + m * 4][c]) * wv;
  }
  float bv = bo[l];
  #pragma unroll
  for (int m = 0; m < 8; ++m) {
    size_t r = (size_t)(r0 + w + m * 4);
    X[r * ND + l] += acc[m] + bv;
  }
}

// ---- fused LN2 + FF (gelu exact) + residual ----
__global__ __launch_bounds__(256) void k_ff(float* __restrict__ X,
    const float* __restrict__ g, const float* __restrict__ bb,
    const float* __restrict__ W1, const float* __restrict__ b1,
    const float* __restrict__ W2, const float* __restrict__ b2) {
  __shared__ float xn[16][64];
  __shared__ float hl[16][256];
  int t = threadIdx.x;
  int r0 = blockIdx.x * 16;
  if (t < 16) {
    const float* xr = X + (size_t)(r0 + t) * ND;
    float m = 0.f;
    for (int d = 0; d < 64; ++d) m += xr[d];
    m *= (1.f / 64.f);
    float v = 0.f;
    for (int d = 0; d < 64; ++d) { float df = xr[d] - m; v += df * df; }
    v *= (1.f / 64.f);
    float rs = rsqrtf(v + 1e-5f);
    for (int d = 0; d < 64; ++d) xn[t][d] = (xr[d] - m) * rs * g[d] + bb[d];
  }
  __syncthreads();
  float a[16];
  #pragma unroll
  for (int m = 0; m < 16; ++m) a[m] = 0.f;
  for (int d = 0; d < 64; ++d) {
    float wv = W1[d * 256 + t];
    #pragma unroll
    for (int m = 0; m < 16; ++m) a[m] += xn[m][d] * wv;
  }
  float bv = b1[t];
  #pragma unroll
  for (int m = 0; m < 16; ++m) {
    float z = a[m] + bv;
    hl[m][t] = 0.5f * z * (1.f + erff(z * 0.7071067811865476f));  // exact gelu
  }
  __syncthreads();
  int w = t >> 6, l = t & 63;
  float acc[4] = {0.f, 0.f, 0.f, 0.f};
  for (int c = 0; c < 256; ++c) {
    float wv = W2[c * 64 + l];
    #pragma unroll
    for (int m = 0; m < 4; ++m) acc[m] += hl[w + m * 4][c] * wv;
  }
  float b2v = b2[l];
  #pragma unroll
  for (int m = 0; m < 4; ++m) {
    size_t r = (size_t)(r0 + w + m * 4);
    X[r * ND + l] += acc[m] + b2v;
  }
}

// ---- swap cls tokens between streams ----
__global__ void k_xchg(float* __restrict__ X) {
  int i = blockIdx.x * 64 + threadIdx.x;   // b*64 + d
  int b = i >> 6, d = i & 63;
  size_t i0 = (size_t)b * NTOK * ND + d;          // stream 0, n=0
  size_t i1 = (size_t)(64 + b) * NTOK * ND + d;   // stream 1, n=0
  float a = X[i0], c = X[i1];
  X[i0] = c; X[i1] = a;
}

// ---- final: out = h_cls + l_cls ----
__global__ void k_out(const float* __restrict__ X, float* __restrict__ out) {
  int i = blockIdx.x * 64 + threadIdx.x;
  int b = i >> 6, d = i & 63;
  out[i] = X[(size_t)b * NTOK * ND + d] + X[(size_t)(64 + b) * NTOK * ND + d];
}

extern "C" void kernel_launch(void* const* d_in, const int* in_sizes, int n_in,
                              void* d_out, int out_size, void* d_ws, size_t ws_size,
                              hipStream_t stream) {
  const float* hsi   = (const float*)d_in[0];
  const float* lidar = (const float*)d_in[1];
  const float* cls_h = (const float*)d_in[2];
  const float* cls_l = (const float*)d_in[3];
  const float* pos_h = (const float*)d_in[4];
  const float* pos_l = (const float*)d_in[5];
  const float* fmg_w = (const float*)d_in[6];
  const float* ln1_g = (const float*)d_in[7];
  const float* ln1_b = (const float*)d_in[8];
  const float* qkv_w = (const float*)d_in[9];
  const float* out_w = (const float*)d_in[10];
  const float* out_b = (const float*)d_in[11];
  const float* ln2_g = (const float*)d_in[12];
  const float* ln2_b = (const float*)d_in[13];
  const float* ff_w1 = (const float*)d_in[14];
  const float* ff_b1 = (const float*)d_in[15];
  const float* ff_w2 = (const float*)d_in[16];
  const float* ff_b2 = (const float*)d_in[17];

  char* ws = (char*)d_ws;
  float* X      = (float*)ws;                      // 28928*64*4      = 7,405,568 B
  float* sdfm   = (float*)(ws + 7405568);          // 64*64*4         = 16,384 B
  uint16_t* Q   = (uint16_t*)(ws + 7421952);       // 28928*512*2     = 29,622,272 B
  uint16_t* V   = (uint16_t*)(ws + 37044224);      // 28928*512*2     = 29,622,272 B
  uint16_t* O   = Q;   // O aliases Q: each attn block stages its slice into LDS first

  k_dfm<<<NB, 128, 0, stream>>>(hsi, lidar, fmg_w, sdfm);
  k_build<<<NROWS, 64, 0, stream>>>(hsi, cls_h, cls_l, pos_h, pos_l, X);
  for (int pass = 0; pass < 2; ++pass) {
    for (int ly = 0; ly < NDEPTH; ++ly) {
      k_qkv<<<NROWS / 16, 256, 0, stream>>>(X, ln1_g + ly * ND, ln1_b + ly * ND,
                                            qkv_w + (size_t)ly * ND * 3 * NIN, sdfm, Q, V);
      k_attn<<<NSB * NH, 256, 0, stream>>>(Q, V, O);
      k_proj<<<NROWS / 32, 256, 0, stream>>>(O, out_w + (size_t)ly * NIN * ND,
                                             out_b + ly * ND, X);
      k_ff<<<NROWS / 16, 256, 0, stream>>>(X, ln2_g + ly * ND, ln2_b + ly * ND,
                                           ff_w1 + (size_t)ly * ND * NMLP, ff_b1 + ly * NMLP,
                                           ff_w2 + (size_t)ly * NMLP * ND, ff_b2 + ly * ND);
    }
    if (pass == 0) k_xchg<<<64, 64, 0, stream>>>(X);
  }
  k_out<<<64, 64, 0, stream>>>(X, (float*)d_out);
}

// Round 4
// 1621.868 us; speedup vs baseline: 4.4118x; 1.2418x over previous
//
#include <hip/hip_runtime.h>
#include <hip/hip_bf16.h>
#include <cstdint>

#define NB 64        // batch
#define ND 64        // DIM
#define NH 8         // heads
#define DH 64        // dim_head
#define NIN 512      // inner
#define NMLP 256
#define NDEPTH 4
#define NPATCH 225
#define NTOK 226
#define NSB 128      // 2*B (both streams batched)
#define NROWS (NSB*NTOK)   // 28928

#define QP 64        // attention Qs LDS pitch (bf16 units)
#define VP 240       // attention Vt LDS pitch (bf16 units)

typedef __attribute__((ext_vector_type(8))) short bfrag8;
typedef __attribute__((ext_vector_type(4))) float ffrag4;

__device__ __forceinline__ float b2f(unsigned short h) {
  uint32_t v = ((uint32_t)h) << 16; float f; __builtin_memcpy(&f, &v, 4); return f;
}
__device__ __forceinline__ unsigned short f2b(float f) {
  __hip_bfloat16 h = __float2bfloat16(f);
  unsigned short u; __builtin_memcpy(&u, &h, 2); return u;
}

// ---- fusion-matrix diagonal: sdfm[b][d] = sqrt(sigmoid(x @ fmg_w[:,65d])) ----
__global__ void k_dfm(const float* __restrict__ hsi, const float* __restrict__ lidar,
                      const float* __restrict__ fmg_w, float* __restrict__ sdfm) {
  __shared__ float xc[128];
  int b = blockIdx.x, t = threadIdx.x;
  const float* src = (t < 64) ? hsi : lidar;
  int d = t & 63;
  const float* p = src + ((size_t)b * 64 + d) * NPATCH;
  float s = 0.f;
  for (int i = 0; i < NPATCH; ++i) s += p[i];
  xc[t] = s * (1.0f / 225.0f);
  __syncthreads();
  if (t < 64) {
    float acc = 0.f;
    const float* w = fmg_w + t * 65;       // column 65*t of [128,4096]
    for (int c = 0; c < 128; ++c) acc += xc[c] * w[c * 4096];
    float sg = 1.0f / (1.0f + expf(-acc));
    sdfm[b * 64 + t] = sqrtf(sg);
  }
}

// ---- build X[2B, 226, 64]: cls + patches(from hsi for BOTH streams) + pos ----
__global__ void k_build(const float* __restrict__ hsi,
                        const float* __restrict__ cls_h, const float* __restrict__ cls_l,
                        const float* __restrict__ pos_h, const float* __restrict__ pos_l,
                        float* __restrict__ X) {
  int r = blockIdx.x;                 // sb*226 + n
  int sb = r / NTOK, n = r - sb * NTOK;
  int s = sb >> 6, b = sb & 63;
  int d = threadIdx.x;
  float v;
  if (n == 0) v = s ? cls_l[d] : cls_h[d];
  else        v = hsi[((size_t)b * 64 + d) * NPATCH + (n - 1)];
  const float* pos = s ? pos_l : pos_h;
  X[(size_t)r * ND + d] = v + pos[n * ND + d];
}

// ---- weight convert+transpose to bf16 [col][k] layouts, all layers ----
// Wqv[ly][n<1024][k<64]  n<512 -> q col n ; n>=512 -> v col n+512
// Wo [ly][n<64][k<512]   = out_w[ly][k][n]
// W1 [ly][n<256][k<64]   = ff_w1[ly][k][n]
// W2 [ly][n<64][k<256]   = ff_w2[ly][k][n]
__global__ __launch_bounds__(256) void k_wconv(
    const float* __restrict__ qkv_w, const float* __restrict__ out_w,
    const float* __restrict__ ff_w1, const float* __restrict__ ff_w2,
    uint16_t* __restrict__ Wqv, uint16_t* __restrict__ Wo,
    uint16_t* __restrict__ W1, uint16_t* __restrict__ W2) {
  int i = blockIdx.x * 256 + threadIdx.x;   // grid covers 524288
  if (i < 262144) {
    int ly = i >> 16, rem = i & 65535, n = rem >> 6, k = rem & 63;
    int col = n + ((n >> 9) << 9);          // n<512 ? n : n+512
    Wqv[i] = f2b(qkv_w[((size_t)ly * 64 + k) * 1536 + col]);
  } else if (i < 393216) {
    int j = i - 262144;
    int ly = j >> 15, rem = j & 32767, n = rem >> 9, k = rem & 511;
    Wo[j] = f2b(out_w[((size_t)ly * 512 + k) * 64 + n]);
  } else if (i < 458752) {
    int j = i - 393216;
    int ly = j >> 14, rem = j & 16383, n = rem >> 6, k = rem & 63;
    W1[j] = f2b(ff_w1[((size_t)ly * 64 + k) * 256 + n]);
  } else {
    int j = i - 458752;
    int ly = j >> 14, rem = j & 16383, n = rem >> 8, k = rem & 255;
    W2[j] = f2b(ff_w2[((size_t)ly * 256 + k) * 64 + n]);
  }
}

// ---- MFMA fused LN1 + Q,V projection ----
// grid = 452 row-blocks x 4 col-groups. Block: 64 rows x 256 cols, K=64.
// B-frags straight from global (weights L1/L2-resident). sqrt(dfm*scale)
// folded into Q via 2-row staged sfm table. Output repacked via LDS for
// 16B-coalesced global writes.
__global__ __launch_bounds__(256) void k_qkv(const float* __restrict__ X,
    const float* __restrict__ g, const float* __restrict__ bb,
    const uint16_t* __restrict__ Wt,    // [1024][64] bf16
    const float* __restrict__ sdfm,
    uint16_t* __restrict__ Qg, uint16_t* __restrict__ Vg) {
  __shared__ __align__(16) uint16_t ot[64 * 264];   // 33792 B
  __shared__ __align__(16) uint16_t xa[64 * 72];    // 9216 B (pitch 72: uniform banks)
  __shared__ float mrow[64], rsrow[64];
  __shared__ float sfm2[2][64];
  __shared__ int rowsel[64];
  int blk = blockIdx.x;
  int cg = blk & 3, rb = blk >> 2;
  int r0 = rb * 64, n0 = cg * 256;
  int t = threadIdx.x, w = t >> 6, l = t & 63;
  // LN stats: wave-per-row shuffle reduce (coalesced 256B row reads)
  for (int i = w; i < 64; i += 4) {
    float x = X[(size_t)(r0 + i) * 64 + l];
    float s = x, q = x * x;
    #pragma unroll
    for (int o = 32; o; o >>= 1) { s += __shfl_xor(s, o); q += __shfl_xor(q, o); }
    if (l == 0) {
      float m = s * (1.f / 64.f);
      mrow[i] = m;
      rsrow[i] = rsqrtf(q * (1.f / 64.f) - m * m + 1e-5f);
    }
  }
  if (t < 128) {
    int which = t >> 6, d = t & 63;
    int sbw = r0 / NTOK + which;
    if (sbw > 127) sbw = 127;
    sfm2[which][d] = sdfm[(sbw & 63) * 64 + d] * 0.35355339059327373f; // sqrt(1/8)
  }
  if (t < 64) rowsel[t] = ((r0 + t) / NTOK) != (r0 / NTOK);
  __syncthreads();
  // normalized bf16 A-tile (coalesced reload, b128 LDS writes)
  for (int i = t; i < 512; i += 256) {
    int row = i >> 3, kc = i & 7;
    const float* xr = X + (size_t)(r0 + row) * 64 + kc * 8;
    float m = mrow[row], rs = rsrow[row];
    uint16_t tmp[8];
    #pragma unroll
    for (int j = 0; j < 8; ++j) {
      int k = kc * 8 + j;
      tmp[j] = f2b((xr[j] - m) * rs * g[k] + bb[k]);
    }
    *(uint4*)(xa + row * 72 + kc * 8) = *(const uint4*)tmp;
  }
  __syncthreads();
  int quad = l >> 4, c = l & 15;
  bfrag8 a0 = *(const bfrag8*)(xa + (w * 16 + c) * 72 + quad * 8);
  bfrag8 a1 = *(const bfrag8*)(xa + (w * 16 + c) * 72 + 32 + quad * 8);
  ffrag4 acc[16];
  #pragma unroll
  for (int jt = 0; jt < 16; ++jt) {
    int n = n0 + jt * 16 + c;
    bfrag8 b0 = *(const bfrag8*)(Wt + (size_t)n * 64 + quad * 8);
    bfrag8 b1 = *(const bfrag8*)(Wt + (size_t)n * 64 + 32 + quad * 8);
    ffrag4 z = {0.f, 0.f, 0.f, 0.f};
    z = __builtin_amdgcn_mfma_f32_16x16x32_bf16(a0, b0, z, 0, 0, 0);
    z = __builtin_amdgcn_mfma_f32_16x16x32_bf16(a1, b1, z, 0, 0, 0);
    acc[jt] = z;
  }
  bool isQ = (n0 < 512);
  #pragma unroll
  for (int jt = 0; jt < 16; ++jt) {
    #pragma unroll
    for (int r = 0; r < 4; ++r) {
      int il = w * 16 + quad * 4 + r;
      float vv = acc[jt][r];
      if (isQ) vv *= sfm2[rowsel[il]][(n0 + jt * 16 + c) & 63];
      ot[il * 264 + jt * 16 + c] = f2b(vv);
    }
  }
  __syncthreads();
  uint16_t* dst = (isQ ? Qg : Vg) + (cg & 1) * 256;
  for (int i = t; i < 2048; i += 256) {
    int row = i >> 5, p = i & 31;
    *(uint4*)(dst + (size_t)(r0 + row) * 512 + p * 8) =
        *(const uint4*)(ot + row * 264 + p * 8);
  }
}

// ---- MFMA attention: one block per (sb, h); 4 waves; tokens padded to 240 ----
__global__ __launch_bounds__(256) void k_attn(const uint16_t* __restrict__ Qg,
    const uint16_t* __restrict__ Vg, uint16_t* __restrict__ Og) {
  __shared__ __align__(16) uint16_t qs[240 * QP];   // 30720 B, rows 226..239 zeroed
  __shared__ __align__(16) uint16_t vt[64 * VP];    // 30720 B, cols 226..239 zeroed
  __shared__ __align__(16) uint16_t pb[4][512];     // 4096 B: per-wave P chunk [16][32]
  int bh = blockIdx.x;
  int sb = bh >> 3, h = bh & 7;
  int t = threadIdx.x, w = t >> 6, l = t & 63;
  const uint16_t* Qb = Qg + (size_t)sb * NTOK * NIN + h * DH;
  const uint16_t* Vb = Vg + (size_t)sb * NTOK * NIN + h * DH;

  for (int idx = t; idx < NTOK * 8; idx += 256) {
    int j = idx >> 3, p = idx & 7;
    *(bfrag8*)(qs + j * QP + p * 8) = *(const bfrag8*)(Qb + (size_t)j * NIN + p * 8);
  }
  for (int idx = t; idx < 14 * 8; idx += 256) {
    int j = 226 + (idx >> 3), p = idx & 7;
    *(uint4*)(qs + j * QP + p * 8) = make_uint4(0, 0, 0, 0);
  }
  for (int idx = t; idx < NTOK * 32; idx += 256) {
    int j = idx >> 5, d2 = (idx & 31) << 1;
    uint32_t v2 = *(const uint32_t*)(Vb + (size_t)j * NIN + d2);
    vt[d2 * VP + j]       = (uint16_t)(v2 & 0xffffu);
    vt[(d2 + 1) * VP + j] = (uint16_t)(v2 >> 16);
  }
  for (int idx = t; idx < 64 * 7; idx += 256) {
    int d = idx / 7, c = 226 + 2 * (idx % 7);
    *(uint32_t*)(vt + d * VP + c) = 0;
  }
  __syncthreads();

  int quad = l >> 4, c = l & 15;
  uint16_t* pw = &pb[w][0];

  for (int it = w; it < 15; it += 4) {
    int i0 = it * 16;
    bfrag8 a0 = *(const bfrag8*)(qs + (i0 + c) * QP + quad * 8);
    bfrag8 a1 = *(const bfrag8*)(qs + (i0 + c) * QP + 32 + quad * 8);
    ffrag4 acc[15];
    #pragma unroll
    for (int jt = 0; jt < 15; ++jt) {
      bfrag8 b0 = *(const bfrag8*)(qs + (jt * 16 + c) * QP + quad * 8);
      bfrag8 b1 = *(const bfrag8*)(qs + (jt * 16 + c) * QP + 32 + quad * 8);
      ffrag4 z = {0.f, 0.f, 0.f, 0.f};
      z = __builtin_amdgcn_mfma_f32_16x16x32_bf16(a0, b0, z, 0, 0, 0);
      z = __builtin_amdgcn_mfma_f32_16x16x32_bf16(a1, b1, z, 0, 0, 0);
      acc[jt] = z;
    }
    float rinv[4];
    #pragma unroll
    for (int r = 0; r < 4; ++r) {
      float m = -1e30f;
      #pragma unroll
      for (int jt = 0; jt < 15; ++jt) m = fmaxf(m, acc[jt][r]);
      #pragma unroll
      for (int o = 8; o; o >>= 1) m = fmaxf(m, __shfl_xor(m, o));
      float s = 0.f;
      #pragma unroll
      for (int jt = 0; jt < 15; ++jt) {
        float p = __expf(acc[jt][r] - m);
        if (jt == 14 && c >= 2) p = 0.f;   // j = 224+c >= 226 invalid
        acc[jt][r] = p;
        s += p;
      }
      #pragma unroll
      for (int o = 8; o; o >>= 1) s += __shfl_xor(s, o);
      rinv[r] = 1.f / s;
    }
    ffrag4 oa[4];
    #pragma unroll
    for (int dt = 0; dt < 4; ++dt) oa[dt] = (ffrag4){0.f, 0.f, 0.f, 0.f};
    for (int jc = 0; jc < 8; ++jc) {
      if (jc == 7) {
        *(uint64_t*)(pw + c * 32 + 16 + quad * 4) = 0ull;
      }
      #pragma unroll
      for (int r = 0; r < 4; ++r) {
        int row = quad * 4 + r;
        pw[row * 32 + c] = f2b(acc[2 * jc][r] * rinv[r]);
        if (jc < 7) pw[row * 32 + 16 + c] = f2b(acc[2 * jc + 1][r] * rinv[r]);
      }
      bfrag8 pa = *(const bfrag8*)(pw + c * 32 + quad * 8);
      int j0 = jc * 32;
      #pragma unroll
      for (int dt = 0; dt < 4; ++dt) {
        bfrag8 vb;
        if (jc < 7)
          vb = *(const bfrag8*)(vt + (dt * 16 + c) * VP + j0 + quad * 8);
        else
          vb = *(const bfrag8*)(vt + (dt * 16 + c) * VP + 224 + (quad & 1) * 8);
        oa[dt] = __builtin_amdgcn_mfma_f32_16x16x32_bf16(pa, vb, oa[dt], 0, 0, 0);
      }
    }
    #pragma unroll
    for (int dt = 0; dt < 4; ++dt) {
      #pragma unroll
      for (int r = 0; r < 4; ++r) {
        int i = i0 + quad * 4 + r;
        if (i < NTOK)
          Og[((size_t)sb * NTOK + i) * NIN + h * DH + dt * 16 + c] = f2b(oa[dt][r]);
      }
    }
  }
}

// ---- MFMA out-projection + residual: X += O @ Wo + bo ----
// Zero LDS: A-frags from global O (quad-complementary = full line coalescing),
// B from L2-hot 64KB table. grid = 452, block 64 rows.
__global__ __launch_bounds__(256) void k_proj(const uint16_t* __restrict__ Og,
    const uint16_t* __restrict__ Wot,   // [64][512] bf16
    const float* __restrict__ bo, float* __restrict__ X) {
  int t = threadIdx.x, w = t >> 6, l = t & 63;
  int quad = l >> 4, c = l & 15;
  int r0 = blockIdx.x * 64;
  const uint16_t* orow = Og + (size_t)(r0 + w * 16 + c) * 512 + quad * 8;
  bfrag8 a[16];
  #pragma unroll
  for (int kc = 0; kc < 16; ++kc) a[kc] = *(const bfrag8*)(orow + kc * 32);
  ffrag4 acc[4];
  #pragma unroll
  for (int jt = 0; jt < 4; ++jt) acc[jt] = (ffrag4){0.f, 0.f, 0.f, 0.f};
  #pragma unroll
  for (int kc = 0; kc < 16; ++kc) {
    #pragma unroll
    for (int jt = 0; jt < 4; ++jt) {
      bfrag8 b = *(const bfrag8*)(Wot + (size_t)(jt * 16 + c) * 512 + kc * 32 + quad * 8);
      acc[jt] = __builtin_amdgcn_mfma_f32_16x16x32_bf16(a[kc], b, acc[jt], 0, 0, 0);
    }
  }
  #pragma unroll
  for (int jt = 0; jt < 4; ++jt) {
    float bv = bo[jt * 16 + c];
    #pragma unroll
    for (int r = 0; r < 4; ++r) {
      int il = w * 16 + quad * 4 + r;
      X[(size_t)(r0 + il) * 64 + jt * 16 + c] += acc[jt][r] + bv;
    }
  }
}

// ---- MFMA fused LN2 + FF (gelu exact) + residual. grid 452, 64 rows/block ----
__global__ __launch_bounds__(256) void k_ff(float* __restrict__ X,
    const float* __restrict__ g, const float* __restrict__ bb,
    const uint16_t* __restrict__ W1t,   // [256][64] bf16
    const float* __restrict__ b1,
    const uint16_t* __restrict__ W2t,   // [64][256] bf16
    const float* __restrict__ b2) {
  __shared__ __align__(16) uint16_t xa[64 * 72];    // 9216 B
  __shared__ __align__(16) uint16_t ha[64 * 264];   // 33792 B (pitch 264: uniform banks)
  __shared__ float mrow[64], rsrow[64];
  int t = threadIdx.x, w = t >> 6, l = t & 63;
  int r0 = blockIdx.x * 64;
  for (int i = w; i < 64; i += 4) {
    float x = X[(size_t)(r0 + i) * 64 + l];
    float s = x, q = x * x;
    #pragma unroll
    for (int o = 32; o; o >>= 1) { s += __shfl_xor(s, o); q += __shfl_xor(q, o); }
    if (l == 0) {
      float m = s * (1.f / 64.f);
      mrow[i] = m;
      rsrow[i] = rsqrtf(q * (1.f / 64.f) - m * m + 1e-5f);
    }
  }
  __syncthreads();
  for (int i = t; i < 512; i += 256) {
    int row = i >> 3, kc = i & 7;
    const float* xr = X + (size_t)(r0 + row) * 64 + kc * 8;
    float m = mrow[row], rs = rsrow[row];
    uint16_t tmp[8];
    #pragma unroll
    for (int j = 0; j < 8; ++j) {
      int k = kc * 8 + j;
      tmp[j] = f2b((xr[j] - m) * rs * g[k] + bb[k]);
    }
    *(uint4*)(xa + row * 72 + kc * 8) = *(const uint4*)tmp;
  }
  __syncthreads();
  int quad = l >> 4, c = l & 15;
  bfrag8 a0 = *(const bfrag8*)(xa + (w * 16 + c) * 72 + quad * 8);
  bfrag8 a1 = *(const bfrag8*)(xa + (w * 16 + c) * 72 + 32 + quad * 8);
  // GEMM1: [64x64] @ [64x256]
  ffrag4 acc[16];
  #pragma unroll
  for (int jt = 0; jt < 16; ++jt) {
    bfrag8 b0 = *(const bfrag8*)(W1t + (size_t)(jt * 16 + c) * 64 + quad * 8);
    bfrag8 b1f = *(const bfrag8*)(W1t + (size_t)(jt * 16 + c) * 64 + 32 + quad * 8);
    ffrag4 z = {0.f, 0.f, 0.f, 0.f};
    z = __builtin_amdgcn_mfma_f32_16x16x32_bf16(a0, b0, z, 0, 0, 0);
    z = __builtin_amdgcn_mfma_f32_16x16x32_bf16(a1, b1f, z, 0, 0, 0);
    acc[jt] = z;
  }
  // gelu (exact erf) -> ha in A-layout
  #pragma unroll
  for (int jt = 0; jt < 16; ++jt) {
    float bv = b1[jt * 16 + c];
    #pragma unroll
    for (int r = 0; r < 4; ++r) {
      int il = w * 16 + quad * 4 + r;
      float z = acc[jt][r] + bv;
      float hg = 0.5f * z * (1.f + erff(z * 0.7071067811865476f));
      ha[il * 264 + jt * 16 + c] = f2b(hg);
    }
  }
  __syncthreads();
  // GEMM2: [64x256] @ [256x64]
  ffrag4 o2[4];
  #pragma unroll
  for (int jt = 0; jt < 4; ++jt) o2[jt] = (ffrag4){0.f, 0.f, 0.f, 0.f};
  #pragma unroll
  for (int kc = 0; kc < 8; ++kc) {
    bfrag8 pa = *(const bfrag8*)(ha + (w * 16 + c) * 264 + kc * 32 + quad * 8);
    #pragma unroll
    for (int jt = 0; jt < 4; ++jt) {
      bfrag8 vb = *(const bfrag8*)(W2t + (size_t)(jt * 16 + c) * 256 + kc * 32 + quad * 8);
      o2[jt] = __builtin_amdgcn_mfma_f32_16x16x32_bf16(pa, vb, o2[jt], 0, 0, 0);
    }
  }
  #pragma unroll
  for (int jt = 0; jt < 4; ++jt) {
    float bv = b2[jt * 16 + c];
    #pragma unroll
    for (int r = 0; r < 4; ++r) {
      int il = w * 16 + quad * 4 + r;
      X[(size_t)(r0 + il) * 64 + jt * 16 + c] += o2[jt][r] + bv;
    }
  }
}

// ---- swap cls tokens between streams ----
__global__ void k_xchg(float* __restrict__ X) {
  int i = blockIdx.x * 64 + threadIdx.x;   // b*64 + d
  int b = i >> 6, d = i & 63;
  size_t i0 = (size_t)b * NTOK * ND + d;
  size_t i1 = (size_t)(64 + b) * NTOK * ND + d;
  float a = X[i0], c = X[i1];
  X[i0] = c; X[i1] = a;
}

// ---- final: out = h_cls + l_cls ----
__global__ void k_out(const float* __restrict__ X, float* __restrict__ out) {
  int i = blockIdx.x * 64 + threadIdx.x;
  int b = i >> 6, d = i & 63;
  out[i] = X[(size_t)b * NTOK * ND + d] + X[(size_t)(64 + b) * NTOK * ND + d];
}

extern "C" void kernel_launch(void* const* d_in, const int* in_sizes, int n_in,
                              void* d_out, int out_size, void* d_ws, size_t ws_size,
                              hipStream_t stream) {
  const float* hsi   = (const float*)d_in[0];
  const float* lidar = (const float*)d_in[1];
  const float* cls_h = (const float*)d_in[2];
  const float* cls_l = (const float*)d_in[3];
  const float* pos_h = (const float*)d_in[4];
  const float* pos_l = (const float*)d_in[5];
  const float* fmg_w = (const float*)d_in[6];
  const float* ln1_g = (const float*)d_in[7];
  const float* ln1_b = (const float*)d_in[8];
  const float* qkv_w = (const float*)d_in[9];
  const float* out_w = (const float*)d_in[10];
  const float* out_b = (const float*)d_in[11];
  const float* ln2_g = (const float*)d_in[12];
  const float* ln2_b = (const float*)d_in[13];
  const float* ff_w1 = (const float*)d_in[14];
  const float* ff_b1 = (const float*)d_in[15];
  const float* ff_w2 = (const float*)d_in[16];
  const float* ff_b2 = (const float*)d_in[17];

  char* ws = (char*)d_ws;
  float* X      = (float*)ws;                      // 7,405,568 B
  float* sdfm   = (float*)(ws + 7405568);          // 16,384 B
  uint16_t* Q   = (uint16_t*)(ws + 7421952);       // 29,622,272 B
  uint16_t* V   = (uint16_t*)(ws + 37044224);      // 29,622,272 B
  uint16_t* O   = Q;                               // O aliases Q (attn stages first)
  uint16_t* Wqv = (uint16_t*)(ws + 66666496);      // 524,288 B
  uint16_t* Wo  = (uint16_t*)(ws + 67190784);      // 262,144 B
  uint16_t* W1  = (uint16_t*)(ws + 67452928);      // 131,072 B
  uint16_t* W2  = (uint16_t*)(ws + 67584000);      // 131,072 B -> end 67,715,072

  k_wconv<<<2048, 256, 0, stream>>>(qkv_w, out_w, ff_w1, ff_w2, Wqv, Wo, W1, W2);
  k_dfm<<<NB, 128, 0, stream>>>(hsi, lidar, fmg_w, sdfm);
  k_build<<<NROWS, 64, 0, stream>>>(hsi, cls_h, cls_l, pos_h, pos_l, X);
  for (int pass = 0; pass < 2; ++pass) {
    for (int ly = 0; ly < NDEPTH; ++ly) {
      k_qkv<<<452 * 4, 256, 0, stream>>>(X, ln1_g + ly * ND, ln1_b + ly * ND,
                                         Wqv + (size_t)ly * 65536, sdfm, Q, V);
      k_attn<<<NSB * NH, 256, 0, stream>>>(Q, V, O);
      k_proj<<<452, 256, 0, stream>>>(O, Wo + (size_t)ly * 32768,
                                      out_b + ly * ND, X);
      k_ff<<<452, 256, 0, stream>>>(X, ln2_g + ly * ND, ln2_b + ly * ND,
                                    W1 + (size_t)ly * 16384, ff_b1 + ly * NMLP,
                                    W2 + (size_t)ly * 16384, ff_b2 + ly * ND);
    }
    if (pass == 0) k_xchg<<<64, 64, 0, stream>>>(X);
  }
  k_out<<<64, 64, 0, stream>>>(X, (float*)d_out);
}

// Round 5
// 897.835 us; speedup vs baseline: 7.9696x; 1.8064x over previous
//
#include <hip/hip_runtime.h>
#include <hip/hip_bf16.h>
#include <cstdint>

#define NB 64        // batch
#define ND 64        // DIM
#define NH 8         // heads
#define DH 64        // dim_head
#define NIN 512      // inner
#define NMLP 256
#define NDEPTH 4
#define NPATCH 225
#define NTOK 226
#define NSB 128      // 2*B (both streams batched)
#define NROWS (NSB*NTOK)   // 28928

#define VP 240       // attention Vt LDS pitch (bf16 units)

typedef __attribute__((ext_vector_type(8))) short bfrag8;
typedef __attribute__((ext_vector_type(4))) float ffrag4;

__device__ __forceinline__ unsigned short f2b(float f) {
  __hip_bfloat16 h = __float2bfloat16(f);
  unsigned short u; __builtin_memcpy(&u, &h, 2); return u;
}

// ---- fusion-matrix diagonal: sdfm[b][d] = sqrt(sigmoid(x @ fmg_w[:,65d])) ----
__global__ void k_dfm(const float* __restrict__ hsi, const float* __restrict__ lidar,
                      const float* __restrict__ fmg_w, float* __restrict__ sdfm) {
  __shared__ float xc[128];
  int b = blockIdx.x, t = threadIdx.x;
  const float* src = (t < 64) ? hsi : lidar;
  int d = t & 63;
  const float* p = src + ((size_t)b * 64 + d) * NPATCH;
  float s = 0.f;
  for (int i = 0; i < NPATCH; ++i) s += p[i];
  xc[t] = s * (1.0f / 225.0f);
  __syncthreads();
  if (t < 64) {
    float acc = 0.f;
    const float* w = fmg_w + t * 65;       // column 65*t of [128,4096]
    for (int c = 0; c < 128; ++c) acc += xc[c] * w[c * 4096];
    float sg = 1.0f / (1.0f + expf(-acc));
    sdfm[b * 64 + t] = sqrtf(sg);
  }
}

// ---- build X[2B,226,64] (+ pos) and Xn = LN1_0(X); one wave per row ----
__global__ void k_build(const float* __restrict__ hsi,
                        const float* __restrict__ cls_h, const float* __restrict__ cls_l,
                        const float* __restrict__ pos_h, const float* __restrict__ pos_l,
                        const float* __restrict__ g, const float* __restrict__ bb,
                        float* __restrict__ X, uint16_t* __restrict__ Xn) {
  int r = blockIdx.x;                 // sb*226 + n
  int sb = r / NTOK, n = r - sb * NTOK;
  int s = sb >> 6, b = sb & 63;
  int d = threadIdx.x;                // 64 threads = 1 wave
  float v;
  if (n == 0) v = s ? cls_l[d] : cls_h[d];
  else        v = hsi[((size_t)b * 64 + d) * NPATCH + (n - 1)];
  v += (s ? pos_l : pos_h)[n * ND + d];
  X[(size_t)r * ND + d] = v;
  float sm = v, sq = v * v;
  #pragma unroll
  for (int o = 32; o; o >>= 1) { sm += __shfl_xor(sm, o); sq += __shfl_xor(sq, o); }
  float m = sm * (1.f / 64.f);
  float rs = rsqrtf(sq * (1.f / 64.f) - m * m + 1e-5f);
  Xn[(size_t)r * ND + d] = f2b((v - m) * rs * g[d] + bb[d]);
}

// ---- weight convert+transpose to bf16 [col][k] layouts, all layers ----
__global__ __launch_bounds__(256) void k_wconv(
    const float* __restrict__ qkv_w, const float* __restrict__ out_w,
    const float* __restrict__ ff_w1, const float* __restrict__ ff_w2,
    uint16_t* __restrict__ Wqv, uint16_t* __restrict__ Wo,
    uint16_t* __restrict__ W1, uint16_t* __restrict__ W2) {
  int i = blockIdx.x * 256 + threadIdx.x;   // grid covers 524288
  if (i < 262144) {
    int ly = i >> 16, rem = i & 65535, n = rem >> 6, k = rem & 63;
    int col = n + ((n >> 9) << 9);          // n<512 ? q col n : v col n+512
    Wqv[i] = f2b(qkv_w[((size_t)ly * 64 + k) * 1536 + col]);
  } else if (i < 393216) {
    int j = i - 262144;
    int ly = j >> 15, rem = j & 32767, n = rem >> 9, k = rem & 511;
    Wo[j] = f2b(out_w[((size_t)ly * 512 + k) * 64 + n]);
  } else if (i < 458752) {
    int j = i - 393216;
    int ly = j >> 14, rem = j & 16383, n = rem >> 6, k = rem & 63;
    W1[j] = f2b(ff_w1[((size_t)ly * 64 + k) * 256 + n]);
  } else {
    int j = i - 458752;
    int ly = j >> 14, rem = j & 16383, n = rem >> 8, k = rem & 255;
    W2[j] = f2b(ff_w2[((size_t)ly * 256 + k) * 64 + n]);
  }
}

// ---- fused QV-projection + MFMA attention: one block per (sb, h) ----
// Phase 1: Q_h = Xn @ Wq_h (scaled by sqrt(dfm)*sqrt(1/8)) -> qs (XOR-swizzled),
//          V_h = Xn @ Wv_h -> vt transposed. A-frags from global Xn (L3-hot),
//          B-frags from global bf16 weights (L1-hot). Rows >225 clamp to 225
//          (dupes masked by the j>=226 softmax mask; i-pads never stored).
// Phase 2: S = Qs Qs^T, softmax, PV (R3/R4-validated code, swizzled qs reads).
// LDS = 30720 + 30720 + 4096 = 65536 B exactly.
__global__ __launch_bounds__(256) void k_fattn(const uint16_t* __restrict__ Xn,
    const uint16_t* __restrict__ Wqv,   // [1024][64] this layer
    const float* __restrict__ sdfm, uint16_t* __restrict__ Og) {
  __shared__ __align__(16) uint16_t qs[240 * 64];
  __shared__ __align__(16) uint16_t vt[64 * VP];
  __shared__ __align__(16) uint16_t pb[4][512];
  int bh = blockIdx.x;
  int sb = bh >> 3, h = bh & 7;
  int t = threadIdx.x, w = t >> 6, l = t & 63;
  int quad = l >> 4, c = l & 15;
  const uint16_t* Xb = Xn + (size_t)sb * NTOK * ND;

  float sf[4];
  #pragma unroll
  for (int dt = 0; dt < 4; ++dt)
    sf[dt] = sdfm[(sb & 63) * 64 + dt * 16 + c] * 0.35355339059327373f;  // sqrt(1/8)

  // phase 1: Q,V projection for this head
  for (int it = w; it < 15; it += 4) {
    int i0 = it * 16;
    int ri = i0 + c; if (ri > 225) ri = 225;
    bfrag8 a0 = *(const bfrag8*)(Xb + (size_t)ri * 64 + quad * 8);
    bfrag8 a1 = *(const bfrag8*)(Xb + (size_t)ri * 64 + 32 + quad * 8);
    #pragma unroll
    for (int dt = 0; dt < 4; ++dt) {
      int nq = h * 64 + dt * 16 + c;
      bfrag8 bq0 = *(const bfrag8*)(Wqv + (size_t)nq * 64 + quad * 8);
      bfrag8 bq1 = *(const bfrag8*)(Wqv + (size_t)nq * 64 + 32 + quad * 8);
      ffrag4 zq = {0.f, 0.f, 0.f, 0.f};
      zq = __builtin_amdgcn_mfma_f32_16x16x32_bf16(a0, bq0, zq, 0, 0, 0);
      zq = __builtin_amdgcn_mfma_f32_16x16x32_bf16(a1, bq1, zq, 0, 0, 0);
      bfrag8 bv0 = *(const bfrag8*)(Wqv + (size_t)(512 + nq) * 64 + quad * 8);
      bfrag8 bv1 = *(const bfrag8*)(Wqv + (size_t)(512 + nq) * 64 + 32 + quad * 8);
      ffrag4 zv = {0.f, 0.f, 0.f, 0.f};
      zv = __builtin_amdgcn_mfma_f32_16x16x32_bf16(a0, bv0, zv, 0, 0, 0);
      zv = __builtin_amdgcn_mfma_f32_16x16x32_bf16(a1, bv1, zv, 0, 0, 0);
      int d = dt * 16 + c;
      #pragma unroll
      for (int r = 0; r < 4; ++r) {
        int i = i0 + quad * 4 + r;
        // qs XOR-swizzle: element (i,d) -> i*64 + ((d>>3 ^ (i&7))<<3) + (d&7)
        qs[i * 64 + ((((d >> 3) ^ (i & 7))) << 3) + (d & 7)] = f2b(zq[r] * sf[dt]);
        vt[d * VP + i] = f2b(zv[r]);
      }
    }
  }
  __syncthreads();

  uint16_t* pw = &pb[w][0];
  for (int it = w; it < 15; it += 4) {
    int i0 = it * 16;
    int ra = i0 + c, sa = ra & 7;
    bfrag8 a0 = *(const bfrag8*)(qs + ra * 64 + ((quad ^ sa) << 3));
    bfrag8 a1 = *(const bfrag8*)(qs + ra * 64 + (((quad + 4) ^ sa) << 3));
    ffrag4 acc[15];
    #pragma unroll
    for (int jt = 0; jt < 15; ++jt) {
      int rb = jt * 16 + c, sk = rb & 7;
      bfrag8 b0 = *(const bfrag8*)(qs + rb * 64 + ((quad ^ sk) << 3));
      bfrag8 b1 = *(const bfrag8*)(qs + rb * 64 + (((quad + 4) ^ sk) << 3));
      ffrag4 z = {0.f, 0.f, 0.f, 0.f};
      z = __builtin_amdgcn_mfma_f32_16x16x32_bf16(a0, b0, z, 0, 0, 0);
      z = __builtin_amdgcn_mfma_f32_16x16x32_bf16(a1, b1, z, 0, 0, 0);
      acc[jt] = z;
    }
    float rinv[4];
    #pragma unroll
    for (int r = 0; r < 4; ++r) {
      float m = -1e30f;
      #pragma unroll
      for (int jt = 0; jt < 15; ++jt) m = fmaxf(m, acc[jt][r]);
      #pragma unroll
      for (int o = 8; o; o >>= 1) m = fmaxf(m, __shfl_xor(m, o));
      float s = 0.f;
      #pragma unroll
      for (int jt = 0; jt < 15; ++jt) {
        float p = __expf(acc[jt][r] - m);
        if (jt == 14 && c >= 2) p = 0.f;   // j = 224+c >= 226 invalid
        acc[jt][r] = p;
        s += p;
      }
      #pragma unroll
      for (int o = 8; o; o >>= 1) s += __shfl_xor(s, o);
      rinv[r] = 1.f / s;
    }
    ffrag4 oa[4];
    #pragma unroll
    for (int dt = 0; dt < 4; ++dt) oa[dt] = (ffrag4){0.f, 0.f, 0.f, 0.f};
    for (int jc = 0; jc < 8; ++jc) {
      if (jc == 7) {
        *(uint64_t*)(pw + c * 32 + 16 + quad * 4) = 0ull;   // zero P cols 16..31
      }
      #pragma unroll
      for (int r = 0; r < 4; ++r) {
        int row = quad * 4 + r;
        pw[row * 32 + c] = f2b(acc[2 * jc][r] * rinv[r]);
        if (jc < 7) pw[row * 32 + 16 + c] = f2b(acc[2 * jc + 1][r] * rinv[r]);
      }
      bfrag8 pa = *(const bfrag8*)(pw + c * 32 + quad * 8);
      int j0 = jc * 32;
      #pragma unroll
      for (int dt = 0; dt < 4; ++dt) {
        bfrag8 vb;
        if (jc < 7)
          vb = *(const bfrag8*)(vt + (dt * 16 + c) * VP + j0 + quad * 8);
        else
          vb = *(const bfrag8*)(vt + (dt * 16 + c) * VP + 224 + (quad & 1) * 8);
        oa[dt] = __builtin_amdgcn_mfma_f32_16x16x32_bf16(pa, vb, oa[dt], 0, 0, 0);
      }
    }
    #pragma unroll
    for (int dt = 0; dt < 4; ++dt) {
      #pragma unroll
      for (int r = 0; r < 4; ++r) {
        int i = i0 + quad * 4 + r;
        if (i < NTOK)
          Og[((size_t)sb * NTOK + i) * NIN + h * DH + dt * 16 + c] = f2b(oa[dt][r]);
      }
    }
  }
}

// ---- MFMA out-projection + residual + LN2 emission ----
// X_mid = X + O@Wo + bo (fp32, stored), Xn2 = LN2(X_mid) bf16 (stored).
__global__ __launch_bounds__(256) void k_proj(const uint16_t* __restrict__ Og,
    const uint16_t* __restrict__ Wot,   // [64][512] bf16
    const float* __restrict__ bo, float* __restrict__ X,
    const float* __restrict__ g2, const float* __restrict__ bb2,
    uint16_t* __restrict__ Xn2) {
  int t = threadIdx.x, w = t >> 6, l = t & 63;
  int quad = l >> 4, c = l & 15;
  int r0 = blockIdx.x * 64;
  const uint16_t* orow = Og + (size_t)(r0 + w * 16 + c) * 512 + quad * 8;
  bfrag8 a[16];
  #pragma unroll
  for (int kc = 0; kc < 16; ++kc) a[kc] = *(const bfrag8*)(orow + kc * 32);
  ffrag4 acc[4];
  #pragma unroll
  for (int jt = 0; jt < 4; ++jt) acc[jt] = (ffrag4){0.f, 0.f, 0.f, 0.f};
  #pragma unroll
  for (int kc = 0; kc < 16; ++kc) {
    #pragma unroll
    for (int jt = 0; jt < 4; ++jt) {
      bfrag8 b = *(const bfrag8*)(Wot + (size_t)(jt * 16 + c) * 512 + kc * 32 + quad * 8);
      acc[jt] = __builtin_amdgcn_mfma_f32_16x16x32_bf16(a[kc], b, acc[jt], 0, 0, 0);
    }
  }
  float xv[4][4];
  #pragma unroll
  for (int jt = 0; jt < 4; ++jt) {
    float bv = bo[jt * 16 + c];
    #pragma unroll
    for (int r = 0; r < 4; ++r) {
      int il = w * 16 + quad * 4 + r;
      size_t idx = (size_t)(r0 + il) * 64 + jt * 16 + c;
      float v = X[idx] + acc[jt][r] + bv;
      X[idx] = v;
      xv[jt][r] = v;
    }
  }
  // LN2 over cols; rows keyed by (w,quad,r), reduce across the 16 c-lanes
  #pragma unroll
  for (int r = 0; r < 4; ++r) {
    float s = xv[0][r] + xv[1][r] + xv[2][r] + xv[3][r];
    float q = xv[0][r]*xv[0][r] + xv[1][r]*xv[1][r] + xv[2][r]*xv[2][r] + xv[3][r]*xv[3][r];
    #pragma unroll
    for (int o = 8; o; o >>= 1) { s += __shfl_xor(s, o); q += __shfl_xor(q, o); }
    float m = s * (1.f / 64.f);
    float rs = rsqrtf(q * (1.f / 64.f) - m * m + 1e-5f);
    int il = w * 16 + quad * 4 + r;
    #pragma unroll
    for (int jt = 0; jt < 4; ++jt) {
      int n = jt * 16 + c;
      Xn2[(size_t)(r0 + il) * 64 + n] = f2b((xv[jt][r] - m) * rs * g2[n] + bb2[n]);
    }
  }
}

// ---- MFMA FF (A-frags from global Xn2) + residual + next-layer LN1 emission ----
__global__ __launch_bounds__(256) void k_ff(float* __restrict__ X,
    const uint16_t* __restrict__ Xn2,
    const uint16_t* __restrict__ W1t,   // [256][64] bf16
    const float* __restrict__ b1,
    const uint16_t* __restrict__ W2t,   // [64][256] bf16
    const float* __restrict__ b2,
    const float* __restrict__ gn, const float* __restrict__ bbn,
    uint16_t* __restrict__ XnOut) {
  __shared__ __align__(16) uint16_t ha[4][16 * 264];   // 33792 B, per-wave h-tile
  int t = threadIdx.x, w = t >> 6, l = t & 63;
  int quad = l >> 4, c = l & 15;
  int r0 = blockIdx.x * 64;
  const uint16_t* xrow = Xn2 + (size_t)(r0 + w * 16 + c) * 64;
  bfrag8 a0 = *(const bfrag8*)(xrow + quad * 8);
  bfrag8 a1 = *(const bfrag8*)(xrow + 32 + quad * 8);
  // GEMM1: [64x64] @ [64x256]
  ffrag4 acc[16];
  #pragma unroll
  for (int jt = 0; jt < 16; ++jt) {
    bfrag8 b0  = *(const bfrag8*)(W1t + (size_t)(jt * 16 + c) * 64 + quad * 8);
    bfrag8 b1f = *(const bfrag8*)(W1t + (size_t)(jt * 16 + c) * 64 + 32 + quad * 8);
    ffrag4 z = {0.f, 0.f, 0.f, 0.f};
    z = __builtin_amdgcn_mfma_f32_16x16x32_bf16(a0, b0, z, 0, 0, 0);
    z = __builtin_amdgcn_mfma_f32_16x16x32_bf16(a1, b1f, z, 0, 0, 0);
    acc[jt] = z;
  }
  // bias + exact gelu -> per-wave A-layout staging
  uint16_t* haw = &ha[w][0];
  #pragma unroll
  for (int jt = 0; jt < 16; ++jt) {
    float bv = b1[jt * 16 + c];
    #pragma unroll
    for (int r = 0; r < 4; ++r) {
      float z = acc[jt][r] + bv;
      float hg = 0.5f * z * (1.f + erff(z * 0.7071067811865476f));
      haw[(quad * 4 + r) * 264 + jt * 16 + c] = f2b(hg);
    }
  }
  __syncthreads();
  // GEMM2: [64x256] @ [256x64]
  ffrag4 o2[4];
  #pragma unroll
  for (int jt = 0; jt < 4; ++jt) o2[jt] = (ffrag4){0.f, 0.f, 0.f, 0.f};
  #pragma unroll
  for (int kc = 0; kc < 8; ++kc) {
    bfrag8 pa = *(const bfrag8*)(haw + c * 264 + kc * 32 + quad * 8);
    #pragma unroll
    for (int jt = 0; jt < 4; ++jt) {
      bfrag8 vb = *(const bfrag8*)(W2t + (size_t)(jt * 16 + c) * 256 + kc * 32 + quad * 8);
      o2[jt] = __builtin_amdgcn_mfma_f32_16x16x32_bf16(pa, vb, o2[jt], 0, 0, 0);
    }
  }
  // residual + store X + next-layer LN1 -> XnOut
  float xv[4][4];
  #pragma unroll
  for (int jt = 0; jt < 4; ++jt) {
    float bv = b2[jt * 16 + c];
    #pragma unroll
    for (int r = 0; r < 4; ++r) {
      int il = w * 16 + quad * 4 + r;
      size_t idx = (size_t)(r0 + il) * 64 + jt * 16 + c;
      float v = X[idx] + o2[jt][r] + bv;
      X[idx] = v;
      xv[jt][r] = v;
    }
  }
  #pragma unroll
  for (int r = 0; r < 4; ++r) {
    float s = xv[0][r] + xv[1][r] + xv[2][r] + xv[3][r];
    float q = xv[0][r]*xv[0][r] + xv[1][r]*xv[1][r] + xv[2][r]*xv[2][r] + xv[3][r]*xv[3][r];
    #pragma unroll
    for (int o = 8; o; o >>= 1) { s += __shfl_xor(s, o); q += __shfl_xor(q, o); }
    float m = s * (1.f / 64.f);
    float rs = rsqrtf(q * (1.f / 64.f) - m * m + 1e-5f);
    int il = w * 16 + quad * 4 + r;
    #pragma unroll
    for (int jt = 0; jt < 4; ++jt) {
      int n = jt * 16 + c;
      XnOut[(size_t)(r0 + il) * 64 + n] = f2b((xv[jt][r] - m) * rs * gn[n] + bbn[n]);
    }
  }
}

// ---- swap cls tokens between streams; refresh Xn (LN1 layer0) for those rows ----
__global__ void k_xchg(float* __restrict__ X, uint16_t* __restrict__ Xn,
                       const float* __restrict__ g, const float* __restrict__ bb) {
  int b = blockIdx.x, d = threadIdx.x;   // 64 blocks x 64 threads (1 wave)
  size_t i0 = (size_t)(b * NTOK) * ND + d;
  size_t i1 = (size_t)((64 + b) * NTOK) * ND + d;
  float a = X[i0], cc = X[i1];
  X[i0] = cc; X[i1] = a;
  float s0 = cc, q0 = cc * cc, s1 = a, q1 = a * a;
  #pragma unroll
  for (int o = 32; o; o >>= 1) {
    s0 += __shfl_xor(s0, o); q0 += __shfl_xor(q0, o);
    s1 += __shfl_xor(s1, o); q1 += __shfl_xor(q1, o);
  }
  float m0 = s0 * (1.f / 64.f), rs0 = rsqrtf(q0 * (1.f / 64.f) - m0 * m0 + 1e-5f);
  float m1 = s1 * (1.f / 64.f), rs1 = rsqrtf(q1 * (1.f / 64.f) - m1 * m1 + 1e-5f);
  Xn[i0] = f2b((cc - m0) * rs0 * g[d] + bb[d]);
  Xn[i1] = f2b((a - m1) * rs1 * g[d] + bb[d]);
}

// ---- final: out = h_cls + l_cls ----
__global__ void k_out(const float* __restrict__ X, float* __restrict__ out) {
  int i = blockIdx.x * 64 + threadIdx.x;
  int b = i >> 6, d = i & 63;
  out[i] = X[(size_t)b * NTOK * ND + d] + X[(size_t)(64 + b) * NTOK * ND + d];
}

extern "C" void kernel_launch(void* const* d_in, const int* in_sizes, int n_in,
                              void* d_out, int out_size, void* d_ws, size_t ws_size,
                              hipStream_t stream) {
  const float* hsi   = (const float*)d_in[0];
  const float* lidar = (const float*)d_in[1];
  const float* cls_h = (const float*)d_in[2];
  const float* cls_l = (const float*)d_in[3];
  const float* pos_h = (const float*)d_in[4];
  const float* pos_l = (const float*)d_in[5];
  const float* fmg_w = (const float*)d_in[6];
  const float* ln1_g = (const float*)d_in[7];
  const float* ln1_b = (const float*)d_in[8];
  const float* qkv_w = (const float*)d_in[9];
  const float* out_w = (const float*)d_in[10];
  const float* out_b = (const float*)d_in[11];
  const float* ln2_g = (const float*)d_in[12];
  const float* ln2_b = (const float*)d_in[13];
  const float* ff_w1 = (const float*)d_in[14];
  const float* ff_b1 = (const float*)d_in[15];
  const float* ff_w2 = (const float*)d_in[16];
  const float* ff_b2 = (const float*)d_in[17];

  char* ws = (char*)d_ws;
  float*    X    = (float*)ws;                       // 7,405,568 B
  float*    sdfm = (float*)(ws + 7405568);           // 16,384 B
  uint16_t* Xn   = (uint16_t*)(ws + 7421952);        // 3,702,784 B
  uint16_t* Xn2  = (uint16_t*)(ws + 11124736);       // 3,702,784 B
  uint16_t* Og   = (uint16_t*)(ws + 14827520);       // 29,622,272 B
  uint16_t* Wqv  = (uint16_t*)(ws + 44449792);       // 524,288 B
  uint16_t* Wo   = (uint16_t*)(ws + 44974080);       // 262,144 B
  uint16_t* W1   = (uint16_t*)(ws + 45236224);       // 131,072 B
  uint16_t* W2   = (uint16_t*)(ws + 45367296);       // 131,072 B -> end 45,498,368

  k_wconv<<<2048, 256, 0, stream>>>(qkv_w, out_w, ff_w1, ff_w2, Wqv, Wo, W1, W2);
  k_dfm<<<NB, 128, 0, stream>>>(hsi, lidar, fmg_w, sdfm);
  k_build<<<NROWS, 64, 0, stream>>>(hsi, cls_h, cls_l, pos_h, pos_l,
                                    ln1_g, ln1_b, X, Xn);
  for (int pass = 0; pass < 2; ++pass) {
    for (int ly = 0; ly < NDEPTH; ++ly) {
      int nx = (ly + 1) & 3;   // next layer's LN1 params (harmless on final layer)
      k_fattn<<<NSB * NH, 256, 0, stream>>>(Xn, Wqv + (size_t)ly * 65536, sdfm, Og);
      k_proj<<<452, 256, 0, stream>>>(Og, Wo + (size_t)ly * 32768, out_b + ly * ND,
                                      X, ln2_g + ly * ND, ln2_b + ly * ND, Xn2);
      k_ff<<<452, 256, 0, stream>>>(X, Xn2,
                                    W1 + (size_t)ly * 16384, ff_b1 + ly * NMLP,
                                    W2 + (size_t)ly * 16384, ff_b2 + ly * ND,
                                    ln1_g + nx * ND, ln1_b + nx * ND, Xn);
    }
    if (pass == 0) k_xchg<<<64, 64, 0, stream>>>(X, Xn, ln1_g, ln1_b);
  }
  k_out<<<64, 64, 0, stream>>>(X, (float*)d_out);
}